// Round 16
// baseline (263.689 us; speedup 1.0000x reference)
//
#include <hip/hip_runtime.h>
#include <hip/hip_bf16.h>
#include <math.h>

typedef short s16x8 __attribute__((ext_vector_type(8)));
typedef float f32x4 __attribute__((ext_vector_type(4)));
typedef int   s32x4 __attribute__((ext_vector_type(4)));

#define DIM 768
#define HEADS 12

static __device__ __forceinline__ short f2bf(float x) {
    union { float f; unsigned u; } v; v.f = x;
    unsigned r = (v.u + 0x7FFF + ((v.u >> 16) & 1)) >> 16;
    return (short)r;
}
static __device__ __forceinline__ float bf2f(short x) {
    union { unsigned u; float f; } v;
    v.u = ((unsigned)(unsigned short)x) << 16;
    return v.f;
}
// packed f32x2 -> bf16x2 (RNE), single HW instr; no builtin on gfx950
static __device__ __forceinline__ unsigned cvt_pk_bf16(float lo, float hi) {
    unsigned r;
    asm("v_cvt_pk_bf16_f32 %0, %1, %2" : "=v"(r) : "v"(lo), "v"(hi));
    return r;
}

// async global->LDS, 16B per lane, wave-uniform LDS base + lane*16
#define GLDS16(g, l) __builtin_amdgcn_global_load_lds( \
    (__attribute__((address_space(1))) void*)(g), \
    (__attribute__((address_space(3))) void*)(l), 16, 0, 0)

// partitioned token t (win*512+n) -> natural token index in [0, 8192)
static __device__ __forceinline__ int nat_row(int t) {
    int w = t >> 9, n = t & 511;
    int b = w >> 3, dO = (w >> 2) & 1, hO = (w >> 1) & 1, wO = w & 1;
    int di = n >> 6, hi = (n >> 3) & 7, wi = n & 7;
    int Dd = dO * 8 + di, Hh = hO * 8 + hi, Ww = wO * 8 + wi;
    return ((b * 16 + Dd) * 16 + Hh) * 16 + Ww;
}

// ---------------- merged weight transpose + fp32->bf16 (all 4 weights) -----
__global__ __launch_bounds__(256) void transpose_all(
    const float* __restrict__ w_qkv, const float* __restrict__ w_proj,
    const float* __restrict__ w1, const float* __restrict__ w2,
    short* __restrict__ oqkv, short* __restrict__ oproj,
    short* __restrict__ o1, short* __restrict__ o2) {
    __shared__ float tile[32][33];
    int b = blockIdx.x;
    const float* in; short* out; int K, N, bx;
    if (b < 1728)      { in = w_qkv;  out = oqkv;  K = 768;  N = 2304; bx = b; }
    else if (b < 2304) { in = w_proj; out = oproj; K = 768;  N = 768;  bx = b - 1728; }
    else if (b < 4608) { in = w1;     out = o1;    K = 768;  N = 3072; bx = b - 2304; }
    else               { in = w2;     out = o2;    K = 3072; N = 768;  bx = b - 4608; }
    int nx = N / 32;
    int n0 = (bx % nx) * 32, k0 = (bx / nx) * 32;
    int tx = threadIdx.x & 31, ty = threadIdx.x >> 5;
#pragma unroll
    for (int j = 0; j < 4; j++) {
        int r = ty + j * 8;
        tile[r][tx] = in[(size_t)(k0 + r) * N + n0 + tx];
    }
    __syncthreads();
#pragma unroll
    for (int j = 0; j < 4; j++) {
        int r = ty + j * 8;
        out[(size_t)(n0 + r) * K + k0 + tx] = f2bf(tile[tx][r]);
    }
}

// ---------------- layernorm (PART=1: window-partition remap of input row) ----
template<int PART>
__global__ __launch_bounds__(256) void ln_kernel(
    const float* __restrict__ x, const float* __restrict__ gw,
    const float* __restrict__ gb, short* __restrict__ out) {
    int t = blockIdx.x;
    int row = PART ? nat_row(t) : t;
    const float* xr = x + (size_t)row * DIM;
    float v0 = xr[threadIdx.x], v1 = xr[threadIdx.x + 256], v2 = xr[threadIdx.x + 512];
    float s1 = v0 + v1 + v2;
    float s2 = v0 * v0 + v1 * v1 + v2 * v2;
#pragma unroll
    for (int o = 32; o > 0; o >>= 1) { s1 += __shfl_down(s1, o); s2 += __shfl_down(s2, o); }
    __shared__ float ws1[4], ws2[4];
    int wid = threadIdx.x >> 6, lane = threadIdx.x & 63;
    if (lane == 0) { ws1[wid] = s1; ws2[wid] = s2; }
    __syncthreads();
    s1 = ws1[0] + ws1[1] + ws1[2] + ws1[3];
    s2 = ws2[0] + ws2[1] + ws2[2] + ws2[3];
    float mean = s1 * (1.f / DIM);
    float var = s2 * (1.f / DIM) - mean * mean;
    float inv = rsqrtf(var + 1e-5f);
    short* orow = out + (size_t)t * DIM;
    orow[threadIdx.x]       = f2bf((v0 - mean) * inv * gw[threadIdx.x]       + gb[threadIdx.x]);
    orow[threadIdx.x + 256] = f2bf((v1 - mean) * inv * gw[threadIdx.x + 256] + gb[threadIdx.x + 256]);
    orow[threadIdx.x + 512] = f2bf((v2 - mean) * inv * gw[threadIdx.x + 512] + gb[threadIdx.x + 512]);
}

// ---------------- GEMM (r7 structure): BK=64 2-phase dbuf, 1 barrier/tile ---
enum { EPI_C = 0, EPI_PROJ = 1, EPI_GELU = 2, EPI_MLP2 = 3 };

template<int EPI, int K, int N, int BN>
__global__ __launch_bounds__(256) void gemm_kernel(
    const short* __restrict__ A, const short* __restrict__ BT,
    const float* __restrict__ bias,
    const float* __restrict__ x_in, float* __restrict__ out_f,
    short* __restrict__ out_b) {
    constexpr int GX = N / BN;
    constexpr int NW = BN / 32;
    constexpr int NT = K / 64;
    __shared__ short As[2][128 * 64];
    __shared__ short Bs[2][BN * 64];
    int flat = blockIdx.x;
    int cpx = gridDim.x >> 3;
    int swz = (flat & 7) * cpx + (flat >> 3);      // XCD-chunk remap
    int tile_n = swz % GX, tile_m = swz / GX;
    int tid = threadIdx.x;
    int wid = tid >> 6, lane = tid & 63, lr = lane & 15, lg = lane >> 4;
    int wr = wid >> 1, wc = wid & 1;
    f32x4 acc[4][NW] = {};
    const short* Arow = A + (size_t)(tile_m * 128) * K;
    const short* Brow = BT + (size_t)(tile_n * BN) * K;
    int swzS = ((lane & 7) ^ (lane >> 3)) * 8;
    const short* gA[4]; int ldsOA[4];
#pragma unroll
    for (int i = 0; i < 4; i++) {
        int row = (i * 256 + tid) >> 3;
        gA[i] = Arow + (size_t)row * K + swzS;
        ldsOA[i] = (i * 256 + wid * 64) * 8;
    }
    const short* gB[NW]; int ldsOB[NW];
#pragma unroll
    for (int i = 0; i < NW; i++) {
        int row = (i * 256 + tid) >> 3;
        gB[i] = Brow + (size_t)row * K + swzS;
        ldsOB[i] = (i * 256 + wid * 64) * 8;
    }
    auto stage = [&](int buf, int k0) {
#pragma unroll
        for (int i = 0; i < 4; i++) GLDS16(gA[i] + k0, &As[buf][ldsOA[i]]);
#pragma unroll
        for (int i = 0; i < NW; i++) GLDS16(gB[i] + k0, &Bs[buf][ldsOB[i]]);
    };
    stage(0, 0);
    __syncthreads();
#pragma unroll 1
    for (int t = 0; t < NT; t++) {
        int cur = t & 1;
        if (t + 1 < NT) stage(cur ^ 1, (t + 1) * 64);
#pragma unroll
        for (int h = 0; h < 2; h++) {
            s16x8 af[4], bfr[NW];
#pragma unroll
            for (int m = 0; m < 4; m++) {
                int row = wr * 64 + m * 16 + lr;
                af[m] = *(const s16x8*)&As[cur][row * 64 + (((h * 4 + lg) ^ (lr & 7)) << 3)];
            }
#pragma unroll
            for (int n = 0; n < NW; n++) {
                int row = wc * (BN / 2) + n * 16 + lr;
                bfr[n] = *(const s16x8*)&Bs[cur][row * 64 + (((h * 4 + lg) ^ (lr & 7)) << 3)];
            }
#pragma unroll
            for (int m = 0; m < 4; m++)
#pragma unroll
                for (int n = 0; n < NW; n++)
                    acc[m][n] = __builtin_amdgcn_mfma_f32_16x16x32_bf16(af[m], bfr[n], acc[m][n], 0, 0, 0);
        }
        __syncthreads();
    }
#pragma unroll
    for (int m = 0; m < 4; m++)
#pragma unroll
        for (int n = 0; n < NW; n++)
#pragma unroll
            for (int r = 0; r < 4; r++) {
                int row = tile_m * 128 + wr * 64 + m * 16 + lg * 4 + r;
                int col = tile_n * BN + wc * (BN / 2) + n * 16 + lr;
                float v = acc[m][n][r] + bias[col];
                if (EPI == EPI_C) {
                    out_b[(size_t)row * N + col] = f2bf(v);
                } else if (EPI == EPI_PROJ) {
                    int nr = nat_row(row);
                    out_f[(size_t)nr * DIM + col] = v + x_in[(size_t)nr * DIM + col];
                } else if (EPI == EPI_GELU) {
                    float u = v * (0.7978845608f + 0.0356774081f * v * v);
                    float e = __expf(2.f * u);
                    float g = v - v * __builtin_amdgcn_rcpf(1.f + e);
                    out_b[(size_t)row * (size_t)N + col] = f2bf(g);
                } else { // EPI_MLP2
                    out_f[(size_t)row * DIM + col] += v;
                }
            }
}

// ---------------- big-tile GEMM: BM=256 x BN=128, wave owns 128x64 ----------
// NEW (r16): triple-buffered depth-2 prefetch with counted vmcnt across raw
// s_barrier (T4). __syncthreads' vmcnt(0) drained the prefetch every iter --
// A streams from HBM (~900cy) with only ~400cy compute cover -> ~500cy/iter
// stall (the measured 28% MfmaUtil). stage(t+2) at iter top; end-of-iter
// vmcnt(6) keeps tile t+2's 6 loads in flight across the barrier. Identical
// per-wave issue order makes each wave's vmcnt(6) certify tiles <= t+1 landed
// for ALL waves. As[(t+2)%3] last read at compute(t-1), which finished before
// the barrier preceding this stage issue -> race-free. No sched_barrier.
template<int EPI, int K, int N>
__global__ __launch_bounds__(256, 2) void gemm_big(
    const short* __restrict__ A, const short* __restrict__ BT,
    const float* __restrict__ bias, short* __restrict__ out_b) {
    constexpr int GX = N / 128;
    constexpr int NT = K / 32;
    __shared__ short As[3][256 * 32];
    __shared__ short Bs[3][128 * 32];
    int flat = blockIdx.x;
    int cpx = gridDim.x >> 3;
    int swz = (flat & 7) * cpx + (flat >> 3);
    int tile_n = swz % GX, tile_m = swz / GX;
    int tid = threadIdx.x;
    int wid = tid >> 6, lane = tid & 63, lr = lane & 15, lg = lane >> 4;
    int wr = wid >> 1, wc = wid & 1;
    f32x4 acc[8][4] = {};
    const short* Arow = A + (size_t)(tile_m * 256) * K;
    const short* Brow = BT + (size_t)(tile_n * 128) * K;
    int srcq = ((tid & 3) ^ ((tid >> 3) & 3)) * 8;
    const short* gA[4]; const short* gB[2];
    int ldsA[4], ldsB[2];
#pragma unroll
    for (int i = 0; i < 4; i++) {
        gA[i] = Arow + (size_t)(i * 64 + (tid >> 2)) * K + srcq;
        ldsA[i] = (i * 256 + wid * 64) * 8;
    }
#pragma unroll
    for (int i = 0; i < 2; i++) {
        gB[i] = Brow + (size_t)(i * 64 + (tid >> 2)) * K + srcq;
        ldsB[i] = (i * 256 + wid * 64) * 8;
    }
    auto stage = [&](int buf, int t) {
        int k0 = t * 32;
#pragma unroll
        for (int i = 0; i < 4; i++) GLDS16(gA[i] + k0, &As[buf][ldsA[i]]);
#pragma unroll
        for (int i = 0; i < 2; i++) GLDS16(gB[i] + k0, &Bs[buf][ldsB[i]]);
    };
    stage(0, 0); stage(1, 1);                       // 12 loads in flight
    asm volatile("s_waitcnt vmcnt(6)" ::: "memory"); // tile 0 landed
    __builtin_amdgcn_s_barrier();
#pragma unroll 1
    for (int t = 0; t < NT; t++) {
        if (t + 2 < NT) stage((t + 2) % 3, t + 2);   // 2-iter lookahead
        int cur = t % 3;
        s16x8 af[8], bfr[4];
#pragma unroll
        for (int m = 0; m < 8; m++) {
            int row = wr * 128 + m * 16 + lr;
            af[m] = *(const s16x8*)&As[cur][row * 32 + ((lg ^ ((lr >> 1) & 3)) << 3)];
        }
#pragma unroll
        for (int n = 0; n < 4; n++) {
            int row = wc * 64 + n * 16 + lr;
            bfr[n] = *(const s16x8*)&Bs[cur][row * 32 + ((lg ^ ((lr >> 1) & 3)) << 3)];
        }
#pragma unroll
        for (int m = 0; m < 8; m++)
#pragma unroll
            for (int n = 0; n < 4; n++)
                acc[m][n] = __builtin_amdgcn_mfma_f32_16x16x32_bf16(af[m], bfr[n], acc[m][n], 0, 0, 0);
        if (t + 1 < NT) {
            if (t + 2 < NT) asm volatile("s_waitcnt vmcnt(6)" ::: "memory"); // t+1 landed, t+2 in flight
            else            asm volatile("s_waitcnt vmcnt(0)" ::: "memory"); // drain tail
            __builtin_amdgcn_s_barrier();
        }
    }
#pragma unroll
    for (int m = 0; m < 8; m++)
#pragma unroll
        for (int n = 0; n < 4; n++)
#pragma unroll
            for (int r = 0; r < 4; r++) {
                int row = tile_m * 256 + wr * 128 + m * 16 + lg * 4 + r;
                int col = tile_n * 128 + wc * 64 + n * 16 + lr;
                float v = acc[m][n][r] + bias[col];
                if (EPI == EPI_C) {
                    out_b[(size_t)row * N + col] = f2bf(v);
                } else { // EPI_GELU
                    float u = v * (0.7978845608f + 0.0356774081f * v * v);
                    float e = __expf(2.f * u);
                    float g = v - v * __builtin_amdgcn_rcpf(1.f + e);
                    out_b[(size_t)row * (size_t)N + col] = f2bf(g);
                }
            }
}

// ---------------- V repack: qkv[t, 1536+h*64+d] -> vt[wh][d][tok] ----------
__global__ __launch_bounds__(256) void repack_vt(
    const short* __restrict__ qkv, short* __restrict__ vt) {
    __shared__ short tile[64][72];
    int ntb = blockIdx.x, wh = blockIdx.y;
    int win = wh / HEADS, h = wh % HEADS;
    const short* vbase = qkv + (size_t)(win * 512 + ntb * 64) * 2304 + 1536 + h * 64;
    int tid = threadIdx.x;
#pragma unroll
    for (int p = 0; p < 2; p++) {
        int idx = tid + p * 256;
        int tok = idx >> 3, vc = idx & 7;
        s16x8 v = *(const s16x8*)&vbase[(size_t)tok * 2304 + vc * 8];
#pragma unroll
        for (int j = 0; j < 8; j++) tile[vc * 8 + j][tok] = v[j];
    }
    __syncthreads();
#pragma unroll
    for (int p = 0; p < 2; p++) {
        int idx = tid + p * 256;
        int d = idx >> 3, vc = idx & 7;
        s16x8 o = *(const s16x8*)&tile[d][vc * 8];
        *(s16x8*)&vt[((size_t)wh * 64 + d) * 512 + ntb * 64 + vc * 8] = o;
    }
}

// ---------------- attention: q-tile 128, MFMA bias prologue, LDS diet ------
__global__ __launch_bounds__(256) void attn_kernel(
    const short* __restrict__ qkv, const short* __restrict__ vt,
    const float* __restrict__ rpd, const float* __restrict__ rph,
    const float* __restrict__ rpw, short* __restrict__ out) {
    __shared__ short pool[16384 + 3072];
    short* KsBuf = pool;             // [2][4096]
    short* VsBuf = pool + 8192;      // [2][4096]
    short* Rs    = VsBuf + 4096;     // aliases Vs[1]; 3072 shorts used
    short* tbd   = pool + 16384;     // [8][128] bf16, log2-domain
    short* tbh   = tbd + 1024;
    short* tbw   = tbd + 2048;
    int wh = blockIdx.x;   // 0..191 (same-KV blocks 192 apart -> same XCD)
    int qt2 = blockIdx.y;  // 0..3
    int win = wh / HEADS, h = wh % HEADS;
    int qbase = qt2 * 128;
    const short* qp = qkv + (size_t)(win * 512) * 2304 + h * 64;  // row stride 2304
    const short* kp = qp + 768;
    const short* vp = vt + (size_t)wh * 64 * 512;
    int tid = threadIdx.x, wid = tid >> 6, lane = tid & 63, lr = lane & 15, lg = lane >> 4;
    const float LOG2E = 1.4426950408889634f;

    s16x8 aq[2][2];
#pragma unroll
    for (int g = 0; g < 2; g++) {
        size_t qoff = (size_t)(qbase + g * 64 + wid * 16 + lr) * 2304;
        aq[g][0] = *(const s16x8*)&qp[qoff + lg * 8];
        aq[g][1] = *(const s16x8*)&qp[qoff + 32 + lg * 8];
    }

    for (int i = tid; i < 48 * 64; i += 256) {
        int row = i >> 6, c = i & 63;
        float v = 0.f;
        if (row < 9)                     v = rpd[(qt2 * 2 + row) * 64 + c];
        else if (row >= 16 && row < 31)  v = rph[(row - 16) * 64 + c];
        else if (row >= 32 && row < 47)  v = rpw[(row - 32) * 64 + c];
        Rs[row * 64 + ((((c >> 3) ^ (row & 7)) << 3) | (c & 7))] = f2bf(v * LOG2E);
    }
    __syncthreads();

    int row0 = wid * 8 + (lane >> 3);
    int swz = ((lane & 7) ^ (row0 & 7)) * 8;
    const short* kSrc0 = kp + (size_t)row0 * 2304 + swz;
    const short* kSrc1 = kp + (size_t)(row0 + 32) * 2304 + swz;
    const short* vSrc0 = vp + (size_t)row0 * 512 + swz;
    const short* vSrc1 = vp + (size_t)(row0 + 32) * 512 + swz;
    int ldsOff0 = wid * 512, ldsOff1 = 2048 + wid * 512;

    GLDS16(kSrc0, &KsBuf[ldsOff0]);
    GLDS16(kSrc1, &KsBuf[ldsOff1]);
    GLDS16(vSrc0, &VsBuf[ldsOff0]);
    GLDS16(vSrc1, &VsBuf[ldsOff1]);

    {
        f32x4 G[3][2];
#pragma unroll
        for (int t = 0; t < 3; t++) {
            int arow = t * 16 + lr;
            s16x8 a0 = *(const s16x8*)&Rs[arow * 64 + ((lg ^ (arow & 7)) << 3)];
            s16x8 a1 = *(const s16x8*)&Rs[arow * 64 + (((4 + lg) ^ (arow & 7)) << 3)];
#pragma unroll
            for (int g = 0; g < 2; g++) {
                f32x4 z = {};
                z = __builtin_amdgcn_mfma_f32_16x16x32_bf16(a0, aq[g][0], z, 0, 0, 0);
                z = __builtin_amdgcn_mfma_f32_16x16x32_bf16(a1, aq[g][1], z, 0, 0, 0);
                G[t][g] = z;
            }
        }
        int qcH = (wid * 2 + (lr >> 3)) & 7;
        int qcW = lr & 7;
#pragma unroll
        for (int g = 0; g < 2; g++) {
            int qr = g * 64 + wid * 16 + lr;
#pragma unroll
            for (int r = 0; r < 4; r++) {
                int j = lg * 4 + r;
                int kd = g + 7 - j;
                if (kd >= 0 && kd < 8) tbd[kd * 128 + qr] = f2bf(G[0][g][r]);
                int kh = qcH + 7 - j;
                if (kh >= 0 && kh < 8) tbh[kh * 128 + qr] = f2bf(G[1][g][r]);
                int kw = qcW + 7 - j;
                if (kw >= 0 && kw < 8) tbw[kw * 128 + qr] = f2bf(G[2][g][r]);
            }
        }
    }
    __syncthreads();   // Rs reads done; tile-0 DMA drained; tables visible

    float m_run[2] = {-1e30f, -1e30f}, l_run[2] = {0.f, 0.f};
    f32x4 accO[2][4] = {};
    int sel = lg >> 1;
    const float SC = 0.125f * LOG2E;

#pragma unroll 1
    for (int kt = 0; kt < 8; kt++) {
        int cur = kt & 1;
        if (kt < 7) {
            size_t kAdv = (size_t)(kt + 1) * 64 * 2304;
            int vAdv = (kt + 1) * 64;
            GLDS16(kSrc0 + kAdv, &KsBuf[(cur ^ 1) * 4096 + ldsOff0]);
            GLDS16(kSrc1 + kAdv, &KsBuf[(cur ^ 1) * 4096 + ldsOff1]);
            GLDS16(vSrc0 + vAdv, &VsBuf[(cur ^ 1) * 4096 + ldsOff0]);
            GLDS16(vSrc1 + vAdv, &VsBuf[(cur ^ 1) * 4096 + ldsOff1]);
        }
        f32x4 sa[2][4];
#pragma unroll
        for (int kn = 0; kn < 4; kn++) {
            int krow = kn * 16 + lr;
            const short* kb_ = &KsBuf[cur * 4096 + krow * 64];
            s16x8 ak0 = *(const s16x8*)&kb_[((lg ^ (krow & 7)) << 3)];
            s16x8 ak1 = *(const s16x8*)&kb_[(((4 + lg) ^ (krow & 7)) << 3)];
#pragma unroll
            for (int g = 0; g < 2; g++) {
                f32x4 z = {};
                z = __builtin_amdgcn_mfma_f32_16x16x32_bf16(ak0, aq[g][0], z, 0, 0, 0);
                z = __builtin_amdgcn_mfma_f32_16x16x32_bf16(ak1, aq[g][1], z, 0, 0, 0);
                sa[g][kn] = z;
            }
        }
        s32x4 pb[2][2];
#pragma unroll
        for (int g = 0; g < 2; g++) {
            int qr = g * 64 + wid * 16 + lr;
            float bdv = bf2f(tbd[kt * 128 + qr]);
            float bb[4], bwv[4];
#pragma unroll
            for (int kn = 0; kn < 4; kn++) bb[kn] = bdv + bf2f(tbh[(2 * kn + sel) * 128 + qr]);
#pragma unroll
            for (int r = 0; r < 4; r++) bwv[r] = bf2f(tbw[(4 * (lg & 1) + r) * 128 + qr]);
            float sv[4][4], mx = -1e30f;
#pragma unroll
            for (int kn = 0; kn < 4; kn++)
#pragma unroll
                for (int r = 0; r < 4; r++) {
                    float vv = sa[g][kn][r] * SC + (bb[kn] + bwv[r]);
                    sv[kn][r] = vv;
                    mx = fmaxf(mx, vv);
                }
            mx = fmaxf(mx, __shfl_xor(mx, 16));
            mx = fmaxf(mx, __shfl_xor(mx, 32));
            float nm = fmaxf(m_run[g], mx);
            float corr = exp2f(m_run[g] - nm);
            m_run[g] = nm;
            float p[4][4], tsum = 0.f;
#pragma unroll
            for (int kn = 0; kn < 4; kn++)
#pragma unroll
                for (int r = 0; r < 4; r++) {
                    float pv = exp2f(sv[kn][r] - nm);
                    p[kn][r] = pv; tsum += pv;
                }
            tsum += __shfl_xor(tsum, 16);
            tsum += __shfl_xor(tsum, 32);
            l_run[g] = l_run[g] * corr + tsum;
#pragma unroll
            for (int n = 0; n < 4; n++)
#pragma unroll
                for (int r = 0; r < 4; r++) accO[g][n][r] *= corr;
            unsigned u[4][2];
#pragma unroll
            for (int kn = 0; kn < 4; kn++) {
                u[kn][0] = cvt_pk_bf16(p[kn][0], p[kn][1]);
                u[kn][1] = cvt_pk_bf16(p[kn][2], p[kn][3]);
            }
#pragma unroll
            for (int s2 = 0; s2 < 2; s2++)
#pragma unroll
                for (int tp = 0; tp < 2; tp++) {
                    int src = (2 * (lg & 1) + tp) * 16 + lr;
#pragma unroll
                    for (int j = 0; j < 2; j++) {
                        int a0 = __shfl((int)u[2 * s2][j], src);
                        int a1 = __shfl((int)u[2 * s2 + 1][j], src);
                        pb[g][s2][tp * 2 + j] = sel ? a1 : a0;
                    }
                }
        }
#pragma unroll
        for (int s2 = 0; s2 < 2; s2++) {
            s16x8 pb0 = *(s16x8*)&pb[0][s2];
            s16x8 pb1 = *(s16x8*)&pb[1][s2];
#pragma unroll
            for (int n = 0; n < 4; n++) {
                int vrow = n * 16 + lr;
                s16x8 av = *(const s16x8*)&VsBuf[cur * 4096 + vrow * 64 + (((s2 * 4 + lg) ^ (vrow & 7)) << 3)];
                accO[0][n] = __builtin_amdgcn_mfma_f32_16x16x32_bf16(av, pb0, accO[0][n], 0, 0, 0);
                accO[1][n] = __builtin_amdgcn_mfma_f32_16x16x32_bf16(av, pb1, accO[1][n], 0, 0, 0);
            }
        }
        __syncthreads();
    }
#pragma unroll
    for (int g = 0; g < 2; g++) {
        float inv = __builtin_amdgcn_rcpf(l_run[g]);
        int tok = win * 512 + qbase + g * 64 + wid * 16 + lr;
        short* orow = out + (size_t)tok * DIM + h * 64;
#pragma unroll
        for (int n = 0; n < 4; n++)
#pragma unroll
            for (int j = 0; j < 2; j++) {
                unsigned uo = cvt_pk_bf16(accO[g][n][2 * j] * inv, accO[g][n][2 * j + 1] * inv);
                *(unsigned*)&orow[n * 16 + 4 * lg + 2 * j] = uo;
            }
    }
}

// ---------------- launch ----------------
extern "C" void kernel_launch(void* const* d_in, const int* in_sizes, int n_in,
                              void* d_out, int out_size, void* d_ws, size_t ws_size,
                              hipStream_t stream) {
    const float* x      = (const float*)d_in[0];
    const float* w_qkv  = (const float*)d_in[1];
    const float* b_qkv  = (const float*)d_in[2];
    const float* w_proj = (const float*)d_in[3];
    const float* b_proj = (const float*)d_in[4];
    const float* rpd    = (const float*)d_in[5];
    const float* rph    = (const float*)d_in[6];
    const float* rpw    = (const float*)d_in[7];
    const float* n1w    = (const float*)d_in[8];
    const float* n1b    = (const float*)d_in[9];
    const float* n2w    = (const float*)d_in[10];
    const float* n2b    = (const float*)d_in[11];
    const float* w1     = (const float*)d_in[12];
    const float* b1     = (const float*)d_in[13];
    const float* w2     = (const float*)d_in[14];
    const float* b2     = (const float*)d_in[15];
    float* out = (float*)d_out;
    char* ws = (char*)d_ws;
    size_t off = 0;
    auto alloc = [&](size_t bytes) { void* p = ws + off; off += (bytes + 255) & ~255ULL; return p; };
    short* wqkvT  = (short*)alloc((size_t)2304 * 768 * 2);
    short* wprojT = (short*)alloc((size_t)768 * 768 * 2);
    short* w1T    = (short*)alloc((size_t)3072 * 768 * 2);
    short* w2T    = (short*)alloc((size_t)768 * 3072 * 2);
    short* xn1    = (short*)alloc((size_t)8192 * 768 * 2);   // reused as attn-out
    short* qkvC   = (short*)alloc((size_t)8192 * 2304 * 2);
    short* vtb    = (short*)alloc((size_t)192 * 64 * 512 * 2);
    short* xn2    = (short*)alloc((size_t)8192 * 768 * 2);
    short* hid    = (short*)alloc((size_t)8192 * 3072 * 2);
    short* attnout = xn1;

    transpose_all<<<6912, 256, 0, stream>>>(w_qkv, w_proj, w1, w2, wqkvT, wprojT, w1T, w2T);

    ln_kernel<1><<<8192, 256, 0, stream>>>(x, n1w, n1b, xn1);
    gemm_big<EPI_C, 768, 2304><<<576, 256, 0, stream>>>(xn1, wqkvT, b_qkv, qkvC);
    repack_vt<<<dim3(8, 192), 256, 0, stream>>>(qkvC, vtb);
    attn_kernel<<<dim3(192, 4), 256, 0, stream>>>(qkvC, vtb, rpd, rph, rpw, attnout);
    gemm_kernel<EPI_PROJ, 768, 768, 64><<<64 * 12, 256, 0, stream>>>(
        attnout, wprojT, b_proj, x, out, nullptr);
    ln_kernel<0><<<8192, 256, 0, stream>>>(out, n2w, n2b, xn2);
    gemm_big<EPI_GELU, 768, 3072><<<768, 256, 0, stream>>>(xn2, w1T, b1, hid);
    gemm_kernel<EPI_MLP2, 3072, 768, 64><<<64 * 12, 256, 0, stream>>>(
        hid, w2T, b2, nullptr, out, nullptr);
}

// Round 17
// 239.470 us; speedup vs baseline: 1.1011x; 1.1011x over previous
//
#include <hip/hip_runtime.h>
#include <hip/hip_bf16.h>
#include <math.h>

typedef short s16x8 __attribute__((ext_vector_type(8)));
typedef float f32x4 __attribute__((ext_vector_type(4)));
typedef int   s32x4 __attribute__((ext_vector_type(4)));

#define DIM 768
#define HEADS 12

static __device__ __forceinline__ short f2bf(float x) {
    union { float f; unsigned u; } v; v.f = x;
    unsigned r = (v.u + 0x7FFF + ((v.u >> 16) & 1)) >> 16;
    return (short)r;
}
static __device__ __forceinline__ float bf2f(short x) {
    union { unsigned u; float f; } v;
    v.u = ((unsigned)(unsigned short)x) << 16;
    return v.f;
}
// packed f32x2 -> bf16x2 (RNE), single HW instr; no builtin on gfx950
static __device__ __forceinline__ unsigned cvt_pk_bf16(float lo, float hi) {
    unsigned r;
    asm("v_cvt_pk_bf16_f32 %0, %1, %2" : "=v"(r) : "v"(lo), "v"(hi));
    return r;
}

// async global->LDS, 16B per lane, wave-uniform LDS base + lane*16
#define GLDS16(g, l) __builtin_amdgcn_global_load_lds( \
    (__attribute__((address_space(1))) void*)(g), \
    (__attribute__((address_space(3))) void*)(l), 16, 0, 0)

// partitioned token t (win*512+n) -> natural token index in [0, 8192)
static __device__ __forceinline__ int nat_row(int t) {
    int w = t >> 9, n = t & 511;
    int b = w >> 3, dO = (w >> 2) & 1, hO = (w >> 1) & 1, wO = w & 1;
    int di = n >> 6, hi = (n >> 3) & 7, wi = n & 7;
    int Dd = dO * 8 + di, Hh = hO * 8 + hi, Ww = wO * 8 + wi;
    return ((b * 16 + Dd) * 16 + Hh) * 16 + Ww;
}

// ---------------- merged weight transpose + fp32->bf16 (all 4 weights) -----
__global__ __launch_bounds__(256) void transpose_all(
    const float* __restrict__ w_qkv, const float* __restrict__ w_proj,
    const float* __restrict__ w1, const float* __restrict__ w2,
    short* __restrict__ oqkv, short* __restrict__ oproj,
    short* __restrict__ o1, short* __restrict__ o2) {
    __shared__ float tile[32][33];
    int b = blockIdx.x;
    const float* in; short* out; int K, N, bx;
    if (b < 1728)      { in = w_qkv;  out = oqkv;  K = 768;  N = 2304; bx = b; }
    else if (b < 2304) { in = w_proj; out = oproj; K = 768;  N = 768;  bx = b - 1728; }
    else if (b < 4608) { in = w1;     out = o1;    K = 768;  N = 3072; bx = b - 2304; }
    else               { in = w2;     out = o2;    K = 3072; N = 768;  bx = b - 4608; }
    int nx = N / 32;
    int n0 = (bx % nx) * 32, k0 = (bx / nx) * 32;
    int tx = threadIdx.x & 31, ty = threadIdx.x >> 5;
#pragma unroll
    for (int j = 0; j < 4; j++) {
        int r = ty + j * 8;
        tile[r][tx] = in[(size_t)(k0 + r) * N + n0 + tx];
    }
    __syncthreads();
#pragma unroll
    for (int j = 0; j < 4; j++) {
        int r = ty + j * 8;
        out[(size_t)(n0 + r) * K + k0 + tx] = f2bf(tile[tx][r]);
    }
}

// ---------------- layernorm (PART=1: window-partition remap of input row) ----
template<int PART>
__global__ __launch_bounds__(256) void ln_kernel(
    const float* __restrict__ x, const float* __restrict__ gw,
    const float* __restrict__ gb, short* __restrict__ out) {
    int t = blockIdx.x;
    int row = PART ? nat_row(t) : t;
    const float* xr = x + (size_t)row * DIM;
    float v0 = xr[threadIdx.x], v1 = xr[threadIdx.x + 256], v2 = xr[threadIdx.x + 512];
    float s1 = v0 + v1 + v2;
    float s2 = v0 * v0 + v1 * v1 + v2 * v2;
#pragma unroll
    for (int o = 32; o > 0; o >>= 1) { s1 += __shfl_down(s1, o); s2 += __shfl_down(s2, o); }
    __shared__ float ws1[4], ws2[4];
    int wid = threadIdx.x >> 6, lane = threadIdx.x & 63;
    if (lane == 0) { ws1[wid] = s1; ws2[wid] = s2; }
    __syncthreads();
    s1 = ws1[0] + ws1[1] + ws1[2] + ws1[3];
    s2 = ws2[0] + ws2[1] + ws2[2] + ws2[3];
    float mean = s1 * (1.f / DIM);
    float var = s2 * (1.f / DIM) - mean * mean;
    float inv = rsqrtf(var + 1e-5f);
    short* orow = out + (size_t)t * DIM;
    orow[threadIdx.x]       = f2bf((v0 - mean) * inv * gw[threadIdx.x]       + gb[threadIdx.x]);
    orow[threadIdx.x + 256] = f2bf((v1 - mean) * inv * gw[threadIdx.x + 256] + gb[threadIdx.x + 256]);
    orow[threadIdx.x + 512] = f2bf((v2 - mean) * inv * gw[threadIdx.x + 512] + gb[threadIdx.x + 512]);
}

// ---------------- GEMM (r7 structure): BK=64 2-phase dbuf, 1 barrier/tile ---
enum { EPI_C = 0, EPI_PROJ = 1, EPI_GELU = 2, EPI_MLP2 = 3 };

template<int EPI, int K, int N, int BN>
__global__ __launch_bounds__(256) void gemm_kernel(
    const short* __restrict__ A, const short* __restrict__ BT,
    const float* __restrict__ bias,
    const float* __restrict__ x_in, float* __restrict__ out_f,
    short* __restrict__ out_b) {
    constexpr int GX = N / BN;
    constexpr int NW = BN / 32;
    constexpr int NT = K / 64;
    __shared__ short As[2][128 * 64];
    __shared__ short Bs[2][BN * 64];
    int flat = blockIdx.x;
    int cpx = gridDim.x >> 3;
    int swz = (flat & 7) * cpx + (flat >> 3);      // XCD-chunk remap
    int tile_n = swz % GX, tile_m = swz / GX;
    int tid = threadIdx.x;
    int wid = tid >> 6, lane = tid & 63, lr = lane & 15, lg = lane >> 4;
    int wr = wid >> 1, wc = wid & 1;
    f32x4 acc[4][NW] = {};
    const short* Arow = A + (size_t)(tile_m * 128) * K;
    const short* Brow = BT + (size_t)(tile_n * BN) * K;
    int swzS = ((lane & 7) ^ (lane >> 3)) * 8;
    const short* gA[4]; int ldsOA[4];
#pragma unroll
    for (int i = 0; i < 4; i++) {
        int row = (i * 256 + tid) >> 3;
        gA[i] = Arow + (size_t)row * K + swzS;
        ldsOA[i] = (i * 256 + wid * 64) * 8;
    }
    const short* gB[NW]; int ldsOB[NW];
#pragma unroll
    for (int i = 0; i < NW; i++) {
        int row = (i * 256 + tid) >> 3;
        gB[i] = Brow + (size_t)row * K + swzS;
        ldsOB[i] = (i * 256 + wid * 64) * 8;
    }
    auto stage = [&](int buf, int k0) {
#pragma unroll
        for (int i = 0; i < 4; i++) GLDS16(gA[i] + k0, &As[buf][ldsOA[i]]);
#pragma unroll
        for (int i = 0; i < NW; i++) GLDS16(gB[i] + k0, &Bs[buf][ldsOB[i]]);
    };
    stage(0, 0);
    __syncthreads();
#pragma unroll 1
    for (int t = 0; t < NT; t++) {
        int cur = t & 1;
        if (t + 1 < NT) stage(cur ^ 1, (t + 1) * 64);
#pragma unroll
        for (int h = 0; h < 2; h++) {
            s16x8 af[4], bfr[NW];
#pragma unroll
            for (int m = 0; m < 4; m++) {
                int row = wr * 64 + m * 16 + lr;
                af[m] = *(const s16x8*)&As[cur][row * 64 + (((h * 4 + lg) ^ (lr & 7)) << 3)];
            }
#pragma unroll
            for (int n = 0; n < NW; n++) {
                int row = wc * (BN / 2) + n * 16 + lr;
                bfr[n] = *(const s16x8*)&Bs[cur][row * 64 + (((h * 4 + lg) ^ (lr & 7)) << 3)];
            }
#pragma unroll
            for (int m = 0; m < 4; m++)
#pragma unroll
                for (int n = 0; n < NW; n++)
                    acc[m][n] = __builtin_amdgcn_mfma_f32_16x16x32_bf16(af[m], bfr[n], acc[m][n], 0, 0, 0);
        }
        __syncthreads();
    }
#pragma unroll
    for (int m = 0; m < 4; m++)
#pragma unroll
        for (int n = 0; n < NW; n++)
#pragma unroll
            for (int r = 0; r < 4; r++) {
                int row = tile_m * 128 + wr * 64 + m * 16 + lg * 4 + r;
                int col = tile_n * BN + wc * (BN / 2) + n * 16 + lr;
                float v = acc[m][n][r] + bias[col];
                if (EPI == EPI_C) {
                    out_b[(size_t)row * N + col] = f2bf(v);
                } else if (EPI == EPI_PROJ) {
                    int nr = nat_row(row);
                    out_f[(size_t)nr * DIM + col] = v + x_in[(size_t)nr * DIM + col];
                } else if (EPI == EPI_GELU) {
                    float u = v * (0.7978845608f + 0.0356774081f * v * v);
                    float e = __expf(2.f * u);
                    float g = v - v * __builtin_amdgcn_rcpf(1.f + e);
                    out_b[(size_t)row * (size_t)N + col] = f2bf(g);
                } else { // EPI_MLP2
                    out_f[(size_t)row * DIM + col] += v;
                }
            }
}

// ---------------- big-tile GEMM: BM=256 x BN=128, wave owns 128x64 ----------
// r15 version (best measured: ~55 us QKV/MLP1, MfmaUtil 28%, FETCH 24.8 MB,
// 2 blocks/CU). Triple-buffer counted-vmcnt variant (r16) REGRESSED:
// 72KB LDS -> 1 block/CU, FETCH doubled. Keep 2-phase + occupancy.
template<int EPI, int K, int N>
__global__ __launch_bounds__(256, 2) void gemm_big(
    const short* __restrict__ A, const short* __restrict__ BT,
    const float* __restrict__ bias, short* __restrict__ out_b) {
    constexpr int GX = N / 128;
    constexpr int NT = K / 32;
    __shared__ short As[2][256 * 32];
    __shared__ short Bs[2][128 * 32];
    int flat = blockIdx.x;
    int cpx = gridDim.x >> 3;
    int swz = (flat & 7) * cpx + (flat >> 3);
    int tile_n = swz % GX, tile_m = swz / GX;
    int tid = threadIdx.x;
    int wid = tid >> 6, lane = tid & 63, lr = lane & 15, lg = lane >> 4;
    int wr = wid >> 1, wc = wid & 1;
    f32x4 acc[8][4] = {};
    const short* Arow = A + (size_t)(tile_m * 256) * K;
    const short* Brow = BT + (size_t)(tile_n * 128) * K;
    int srcq = ((tid & 3) ^ ((tid >> 3) & 3)) * 8;
    const short* gA[4]; const short* gB[2];
    int ldsA[4], ldsB[2];
#pragma unroll
    for (int i = 0; i < 4; i++) {
        gA[i] = Arow + (size_t)(i * 64 + (tid >> 2)) * K + srcq;
        ldsA[i] = (i * 256 + wid * 64) * 8;
    }
#pragma unroll
    for (int i = 0; i < 2; i++) {
        gB[i] = Brow + (size_t)(i * 64 + (tid >> 2)) * K + srcq;
        ldsB[i] = (i * 256 + wid * 64) * 8;
    }
    auto stage = [&](int buf, int t) {
        int k0 = t * 32;
#pragma unroll
        for (int i = 0; i < 4; i++) GLDS16(gA[i] + k0, &As[buf][ldsA[i]]);
#pragma unroll
        for (int i = 0; i < 2; i++) GLDS16(gB[i] + k0, &Bs[buf][ldsB[i]]);
    };
    stage(0, 0);
    __syncthreads();
#pragma unroll 1
    for (int t = 0; t < NT; t++) {
        int cur = t & 1;
        if (t + 1 < NT) stage(cur ^ 1, t + 1);
        s16x8 af[8], bfr[4];
#pragma unroll
        for (int m = 0; m < 8; m++) {
            int row = wr * 128 + m * 16 + lr;
            af[m] = *(const s16x8*)&As[cur][row * 32 + ((lg ^ ((lr >> 1) & 3)) << 3)];
        }
#pragma unroll
        for (int n = 0; n < 4; n++) {
            int row = wc * 64 + n * 16 + lr;
            bfr[n] = *(const s16x8*)&Bs[cur][row * 32 + ((lg ^ ((lr >> 1) & 3)) << 3)];
        }
#pragma unroll
        for (int m = 0; m < 8; m++)
#pragma unroll
            for (int n = 0; n < 4; n++)
                acc[m][n] = __builtin_amdgcn_mfma_f32_16x16x32_bf16(af[m], bfr[n], acc[m][n], 0, 0, 0);
        __syncthreads();
    }
#pragma unroll
    for (int m = 0; m < 8; m++)
#pragma unroll
        for (int n = 0; n < 4; n++)
#pragma unroll
            for (int r = 0; r < 4; r++) {
                int row = tile_m * 256 + wr * 128 + m * 16 + lg * 4 + r;
                int col = tile_n * 128 + wc * 64 + n * 16 + lr;
                float v = acc[m][n][r] + bias[col];
                if (EPI == EPI_C) {
                    out_b[(size_t)row * N + col] = f2bf(v);
                } else { // EPI_GELU
                    float u = v * (0.7978845608f + 0.0356774081f * v * v);
                    float e = __expf(2.f * u);
                    float g = v - v * __builtin_amdgcn_rcpf(1.f + e);
                    out_b[(size_t)row * (size_t)N + col] = f2bf(g);
                }
            }
}

// ---------------- V repack: qkv[t, 1536+h*64+d] -> vt[wh][d][tok] ----------
__global__ __launch_bounds__(256) void repack_vt(
    const short* __restrict__ qkv, short* __restrict__ vt) {
    __shared__ short tile[64][72];
    int ntb = blockIdx.x, wh = blockIdx.y;
    int win = wh / HEADS, h = wh % HEADS;
    const short* vbase = qkv + (size_t)(win * 512 + ntb * 64) * 2304 + 1536 + h * 64;
    int tid = threadIdx.x;
#pragma unroll
    for (int p = 0; p < 2; p++) {
        int idx = tid + p * 256;
        int tok = idx >> 3, vc = idx & 7;
        s16x8 v = *(const s16x8*)&vbase[(size_t)tok * 2304 + vc * 8];
#pragma unroll
        for (int j = 0; j < 8; j++) tile[vc * 8 + j][tok] = v[j];
    }
    __syncthreads();
#pragma unroll
    for (int p = 0; p < 2; p++) {
        int idx = tid + p * 256;
        int d = idx >> 3, vc = idx & 7;
        s16x8 o = *(const s16x8*)&tile[d][vc * 8];
        *(s16x8*)&vt[((size_t)wh * 64 + d) * 512 + ntb * 64 + vc * 8] = o;
    }
}

// ---------------- attention: q-tile 128, MFMA bias prologue, LDS diet ------
__global__ __launch_bounds__(256) void attn_kernel(
    const short* __restrict__ qkv, const short* __restrict__ vt,
    const float* __restrict__ rpd, const float* __restrict__ rph,
    const float* __restrict__ rpw, short* __restrict__ out) {
    __shared__ short pool[16384 + 3072];
    short* KsBuf = pool;             // [2][4096]
    short* VsBuf = pool + 8192;      // [2][4096]
    short* Rs    = VsBuf + 4096;     // aliases Vs[1]; 3072 shorts used
    short* tbd   = pool + 16384;     // [8][128] bf16, log2-domain
    short* tbh   = tbd + 1024;
    short* tbw   = tbd + 2048;
    int wh = blockIdx.x;   // 0..191 (same-KV blocks 192 apart -> same XCD)
    int qt2 = blockIdx.y;  // 0..3
    int win = wh / HEADS, h = wh % HEADS;
    int qbase = qt2 * 128;
    const short* qp = qkv + (size_t)(win * 512) * 2304 + h * 64;  // row stride 2304
    const short* kp = qp + 768;
    const short* vp = vt + (size_t)wh * 64 * 512;
    int tid = threadIdx.x, wid = tid >> 6, lane = tid & 63, lr = lane & 15, lg = lane >> 4;
    const float LOG2E = 1.4426950408889634f;

    s16x8 aq[2][2];
#pragma unroll
    for (int g = 0; g < 2; g++) {
        size_t qoff = (size_t)(qbase + g * 64 + wid * 16 + lr) * 2304;
        aq[g][0] = *(const s16x8*)&qp[qoff + lg * 8];
        aq[g][1] = *(const s16x8*)&qp[qoff + 32 + lg * 8];
    }

    for (int i = tid; i < 48 * 64; i += 256) {
        int row = i >> 6, c = i & 63;
        float v = 0.f;
        if (row < 9)                     v = rpd[(qt2 * 2 + row) * 64 + c];
        else if (row >= 16 && row < 31)  v = rph[(row - 16) * 64 + c];
        else if (row >= 32 && row < 47)  v = rpw[(row - 32) * 64 + c];
        Rs[row * 64 + ((((c >> 3) ^ (row & 7)) << 3) | (c & 7))] = f2bf(v * LOG2E);
    }
    __syncthreads();

    int row0 = wid * 8 + (lane >> 3);
    int swz = ((lane & 7) ^ (row0 & 7)) * 8;
    const short* kSrc0 = kp + (size_t)row0 * 2304 + swz;
    const short* kSrc1 = kp + (size_t)(row0 + 32) * 2304 + swz;
    const short* vSrc0 = vp + (size_t)row0 * 512 + swz;
    const short* vSrc1 = vp + (size_t)(row0 + 32) * 512 + swz;
    int ldsOff0 = wid * 512, ldsOff1 = 2048 + wid * 512;

    GLDS16(kSrc0, &KsBuf[ldsOff0]);
    GLDS16(kSrc1, &KsBuf[ldsOff1]);
    GLDS16(vSrc0, &VsBuf[ldsOff0]);
    GLDS16(vSrc1, &VsBuf[ldsOff1]);

    {
        f32x4 G[3][2];
#pragma unroll
        for (int t = 0; t < 3; t++) {
            int arow = t * 16 + lr;
            s16x8 a0 = *(const s16x8*)&Rs[arow * 64 + ((lg ^ (arow & 7)) << 3)];
            s16x8 a1 = *(const s16x8*)&Rs[arow * 64 + (((4 + lg) ^ (arow & 7)) << 3)];
#pragma unroll
            for (int g = 0; g < 2; g++) {
                f32x4 z = {};
                z = __builtin_amdgcn_mfma_f32_16x16x32_bf16(a0, aq[g][0], z, 0, 0, 0);
                z = __builtin_amdgcn_mfma_f32_16x16x32_bf16(a1, aq[g][1], z, 0, 0, 0);
                G[t][g] = z;
            }
        }
        int qcH = (wid * 2 + (lr >> 3)) & 7;
        int qcW = lr & 7;
#pragma unroll
        for (int g = 0; g < 2; g++) {
            int qr = g * 64 + wid * 16 + lr;
#pragma unroll
            for (int r = 0; r < 4; r++) {
                int j = lg * 4 + r;
                int kd = g + 7 - j;
                if (kd >= 0 && kd < 8) tbd[kd * 128 + qr] = f2bf(G[0][g][r]);
                int kh = qcH + 7 - j;
                if (kh >= 0 && kh < 8) tbh[kh * 128 + qr] = f2bf(G[1][g][r]);
                int kw = qcW + 7 - j;
                if (kw >= 0 && kw < 8) tbw[kw * 128 + qr] = f2bf(G[2][g][r]);
            }
        }
    }
    __syncthreads();   // Rs reads done; tile-0 DMA drained; tables visible

    float m_run[2] = {-1e30f, -1e30f}, l_run[2] = {0.f, 0.f};
    f32x4 accO[2][4] = {};
    int sel = lg >> 1;
    const float SC = 0.125f * LOG2E;

#pragma unroll 1
    for (int kt = 0; kt < 8; kt++) {
        int cur = kt & 1;
        if (kt < 7) {
            size_t kAdv = (size_t)(kt + 1) * 64 * 2304;
            int vAdv = (kt + 1) * 64;
            GLDS16(kSrc0 + kAdv, &KsBuf[(cur ^ 1) * 4096 + ldsOff0]);
            GLDS16(kSrc1 + kAdv, &KsBuf[(cur ^ 1) * 4096 + ldsOff1]);
            GLDS16(vSrc0 + vAdv, &VsBuf[(cur ^ 1) * 4096 + ldsOff0]);
            GLDS16(vSrc1 + vAdv, &VsBuf[(cur ^ 1) * 4096 + ldsOff1]);
        }
        f32x4 sa[2][4];
#pragma unroll
        for (int kn = 0; kn < 4; kn++) {
            int krow = kn * 16 + lr;
            const short* kb_ = &KsBuf[cur * 4096 + krow * 64];
            s16x8 ak0 = *(const s16x8*)&kb_[((lg ^ (krow & 7)) << 3)];
            s16x8 ak1 = *(const s16x8*)&kb_[(((4 + lg) ^ (krow & 7)) << 3)];
#pragma unroll
            for (int g = 0; g < 2; g++) {
                f32x4 z = {};
                z = __builtin_amdgcn_mfma_f32_16x16x32_bf16(ak0, aq[g][0], z, 0, 0, 0);
                z = __builtin_amdgcn_mfma_f32_16x16x32_bf16(ak1, aq[g][1], z, 0, 0, 0);
                sa[g][kn] = z;
            }
        }
        s32x4 pb[2][2];
#pragma unroll
        for (int g = 0; g < 2; g++) {
            int qr = g * 64 + wid * 16 + lr;
            float bdv = bf2f(tbd[kt * 128 + qr]);
            float bb[4], bwv[4];
#pragma unroll
            for (int kn = 0; kn < 4; kn++) bb[kn] = bdv + bf2f(tbh[(2 * kn + sel) * 128 + qr]);
#pragma unroll
            for (int r = 0; r < 4; r++) bwv[r] = bf2f(tbw[(4 * (lg & 1) + r) * 128 + qr]);
            float sv[4][4], mx = -1e30f;
#pragma unroll
            for (int kn = 0; kn < 4; kn++)
#pragma unroll
                for (int r = 0; r < 4; r++) {
                    float vv = sa[g][kn][r] * SC + (bb[kn] + bwv[r]);
                    sv[kn][r] = vv;
                    mx = fmaxf(mx, vv);
                }
            mx = fmaxf(mx, __shfl_xor(mx, 16));
            mx = fmaxf(mx, __shfl_xor(mx, 32));
            float nm = fmaxf(m_run[g], mx);
            float corr = exp2f(m_run[g] - nm);
            m_run[g] = nm;
            float p[4][4], tsum = 0.f;
#pragma unroll
            for (int kn = 0; kn < 4; kn++)
#pragma unroll
                for (int r = 0; r < 4; r++) {
                    float pv = exp2f(sv[kn][r] - nm);
                    p[kn][r] = pv; tsum += pv;
                }
            tsum += __shfl_xor(tsum, 16);
            tsum += __shfl_xor(tsum, 32);
            l_run[g] = l_run[g] * corr + tsum;
#pragma unroll
            for (int n = 0; n < 4; n++)
#pragma unroll
                for (int r = 0; r < 4; r++) accO[g][n][r] *= corr;
            unsigned u[4][2];
#pragma unroll
            for (int kn = 0; kn < 4; kn++) {
                u[kn][0] = cvt_pk_bf16(p[kn][0], p[kn][1]);
                u[kn][1] = cvt_pk_bf16(p[kn][2], p[kn][3]);
            }
#pragma unroll
            for (int s2 = 0; s2 < 2; s2++)
#pragma unroll
                for (int tp = 0; tp < 2; tp++) {
                    int src = (2 * (lg & 1) + tp) * 16 + lr;
#pragma unroll
                    for (int j = 0; j < 2; j++) {
                        int a0 = __shfl((int)u[2 * s2][j], src);
                        int a1 = __shfl((int)u[2 * s2 + 1][j], src);
                        pb[g][s2][tp * 2 + j] = sel ? a1 : a0;
                    }
                }
        }
#pragma unroll
        for (int s2 = 0; s2 < 2; s2++) {
            s16x8 pb0 = *(s16x8*)&pb[0][s2];
            s16x8 pb1 = *(s16x8*)&pb[1][s2];
#pragma unroll
            for (int n = 0; n < 4; n++) {
                int vrow = n * 16 + lr;
                s16x8 av = *(const s16x8*)&VsBuf[cur * 4096 + vrow * 64 + (((s2 * 4 + lg) ^ (vrow & 7)) << 3)];
                accO[0][n] = __builtin_amdgcn_mfma_f32_16x16x32_bf16(av, pb0, accO[0][n], 0, 0, 0);
                accO[1][n] = __builtin_amdgcn_mfma_f32_16x16x32_bf16(av, pb1, accO[1][n], 0, 0, 0);
            }
        }
        __syncthreads();
    }
#pragma unroll
    for (int g = 0; g < 2; g++) {
        float inv = __builtin_amdgcn_rcpf(l_run[g]);
        int tok = win * 512 + qbase + g * 64 + wid * 16 + lr;
        short* orow = out + (size_t)tok * DIM + h * 64;
#pragma unroll
        for (int n = 0; n < 4; n++)
#pragma unroll
            for (int j = 0; j < 2; j++) {
                unsigned uo = cvt_pk_bf16(accO[g][n][2 * j] * inv, accO[g][n][2 * j + 1] * inv);
                *(unsigned*)&orow[n * 16 + 4 * lg + 2 * j] = uo;
            }
    }
}

// ---------------- launch ----------------
extern "C" void kernel_launch(void* const* d_in, const int* in_sizes, int n_in,
                              void* d_out, int out_size, void* d_ws, size_t ws_size,
                              hipStream_t stream) {
    const float* x      = (const float*)d_in[0];
    const float* w_qkv  = (const float*)d_in[1];
    const float* b_qkv  = (const float*)d_in[2];
    const float* w_proj = (const float*)d_in[3];
    const float* b_proj = (const float*)d_in[4];
    const float* rpd    = (const float*)d_in[5];
    const float* rph    = (const float*)d_in[6];
    const float* rpw    = (const float*)d_in[7];
    const float* n1w    = (const float*)d_in[8];
    const float* n1b    = (const float*)d_in[9];
    const float* n2w    = (const float*)d_in[10];
    const float* n2b    = (const float*)d_in[11];
    const float* w1     = (const float*)d_in[12];
    const float* b1     = (const float*)d_in[13];
    const float* w2     = (const float*)d_in[14];
    const float* b2     = (const float*)d_in[15];
    float* out = (float*)d_out;
    char* ws = (char*)d_ws;
    size_t off = 0;
    auto alloc = [&](size_t bytes) { void* p = ws + off; off += (bytes + 255) & ~255ULL; return p; };
    short* wqkvT  = (short*)alloc((size_t)2304 * 768 * 2);
    short* wprojT = (short*)alloc((size_t)768 * 768 * 2);
    short* w1T    = (short*)alloc((size_t)3072 * 768 * 2);
    short* w2T    = (short*)alloc((size_t)768 * 3072 * 2);
    short* xn1    = (short*)alloc((size_t)8192 * 768 * 2);   // reused as attn-out
    short* qkvC   = (short*)alloc((size_t)8192 * 2304 * 2);
    short* vtb    = (short*)alloc((size_t)192 * 64 * 512 * 2);
    short* xn2    = (short*)alloc((size_t)8192 * 768 * 2);
    short* hid    = (short*)alloc((size_t)8192 * 3072 * 2);
    short* attnout = xn1;

    transpose_all<<<6912, 256, 0, stream>>>(w_qkv, w_proj, w1, w2, wqkvT, wprojT, w1T, w2T);

    ln_kernel<1><<<8192, 256, 0, stream>>>(x, n1w, n1b, xn1);
    gemm_big<EPI_C, 768, 2304><<<576, 256, 0, stream>>>(xn1, wqkvT, b_qkv, qkvC);
    repack_vt<<<dim3(8, 192), 256, 0, stream>>>(qkvC, vtb);
    attn_kernel<<<dim3(192, 4), 256, 0, stream>>>(qkvC, vtb, rpd, rph, rpw, attnout);
    gemm_kernel<EPI_PROJ, 768, 768, 64><<<64 * 12, 256, 0, stream>>>(
        attnout, wprojT, b_proj, x, out, nullptr);
    ln_kernel<0><<<8192, 256, 0, stream>>>(out, n2w, n2b, xn2);
    gemm_big<EPI_GELU, 768, 3072><<<768, 256, 0, stream>>>(xn2, w1T, b1, hid);
    gemm_kernel<EPI_MLP2, 3072, 768, 64><<<64 * 12, 256, 0, stream>>>(
        hid, w2T, b2, nullptr, out, nullptr);
}